// Round 1
// baseline (449.661 us; speedup 1.0000x reference)
//
#include <hip/hip_runtime.h>

#define NGRAPH 100000
#define NPG 9
#define EPG 36

#define WPB 8                 // waves per block
#define BLOCK (WPB * 64)
#define GRID 1024

// wave-level LDS fence: all lanes lockstep, just drain lgkm
#define WSYNC() asm volatile("s_waitcnt lgkmcnt(0)" ::: "memory")

__device__ __forceinline__ float rl(float v, int l) {
  return __uint_as_float(__builtin_amdgcn_readlane(__float_as_uint(v), l));
}

struct __align__(16) WS {
  float xg[144];   // x tile [9][16]
  float A[108];    // adjacency [9][12] (12-pad -> 16B-aligned rows)
  float deg[12];   // degree -> dinv
  float h1[288];   // relu(conv1) [9][32]
};

__global__ __launch_bounds__(BLOCK, 2) void gqn(
    const float* __restrict__ x,
    const int* __restrict__ ei,
    const float* __restrict__ W1, const float* __restrict__ b1,
    const float* __restrict__ W2, const float* __restrict__ b2,
    const float* __restrict__ fc1w, const float* __restrict__ fc1b,
    const float* __restrict__ fc2w, const float* __restrict__ fc2b,
    float* __restrict__ out)
{
  __shared__ float fc1T[64 * 132];   // fc1_w transposed: [j][k], k-pad 132
  __shared__ WS ws[WPB];

  const int tid  = threadIdx.x;
  const int lane = tid & 63;
  const int wib  = tid >> 6;

  // ---- per-block setup: transpose fc1_w into LDS ----
  for (int idx = tid; idx < 128 * 64; idx += BLOCK) {
    int k = idx >> 6, j = idx & 63;
    fc1T[j * 132 + k] = fc1w[idx];
  }
  __syncthreads();

  // ---- per-lane register weight caches ----
  const int f1 = lane & 31;
  float w1c[16], w2c[32];
#pragma unroll
  for (int k = 0; k < 16; ++k) w1c[k] = W1[k * 32 + f1];
  const float b1c = b1[f1];
#pragma unroll
  for (int k = 0; k < 32; ++k) w2c[k] = W2[k * 64 + lane];
  const float b2c   = b2[lane];
  const float fc1bc = fc1b[lane];
  const float fc2wc = fc2w[lane];
  const float fc2bs = fc2b[0];

  WS* S = &ws[wib];
  const int* srcp = ei;
  const int* dstp = ei + NGRAPH * EPG;
  const int gw = blockIdx.x * WPB + wib;
  const int nw = GRID * WPB;

  for (int g = gw; g < NGRAPH; g += nw) {
    WSYNC();  // fence previous iteration's LDS reads vs. this iteration's writes

    // ---- stage x tile, zero A, init deg, load edges ----
    if (lane < 36) {
      float4 v = ((const float4*)(x + (long)g * 144))[lane];
      ((float4*)S->xg)[lane] = v;
    }
    if (lane < 27) ((float4*)S->A)[lane] = make_float4(0.f, 0.f, 0.f, 0.f);
    if (lane < 9)  S->deg[lane] = 1.0f;   // self-loop
    int es = 0, ed = 0;
    if (lane < 36) {
      es = srcp[g * EPG + lane] - g * NPG;
      ed = dstp[g * EPG + lane] - g * NPG;
    }
    WSYNC();

    if (lane < 36) atomicAdd(&S->deg[ed], 1.0f);
    WSYNC();

    if (lane < 9) S->deg[lane] = 1.0f / sqrtf(S->deg[lane]);  // deg -> dinv
    WSYNC();

    if (lane < 36) {
      float nv = S->deg[es] * S->deg[ed];
      atomicAdd(&S->A[ed * 12 + es], nv);
    }
    if (lane < 9) {
      float dv = S->deg[lane];
      atomicAdd(&S->A[lane * 12 + lane], dv * dv);
    }

    // ---- GCN1 matmul: h1t[n] = x[n,:] . W1[:,f1]  (halves redundant) ----
    float h1t[9];
#pragma unroll
    for (int n = 0; n < 9; ++n) {
      float acc = 0.f;
#pragma unroll
      for (int q = 0; q < 4; ++q) {
        float4 xv = ((const float4*)S->xg)[n * 4 + q];
        acc = fmaf(xv.x, w1c[q * 4 + 0], acc);
        acc = fmaf(xv.y, w1c[q * 4 + 1], acc);
        acc = fmaf(xv.z, w1c[q * 4 + 2], acc);
        acc = fmaf(xv.w, w1c[q * 4 + 3], acc);
      }
      h1t[n] = acc;
    }
    WSYNC();  // A atomics complete

    // ---- GCN1 aggregate + bias + relu -> LDS h1[9][32] ----
#pragma unroll
    for (int n = 0; n < 9; ++n) {
      const float4* Ar = (const float4*)(S->A + n * 12);
      float4 a0 = Ar[0], a1 = Ar[1];
      float  a8 = S->A[n * 12 + 8];
      float acc = b1c;
      acc = fmaf(a0.x, h1t[0], acc);
      acc = fmaf(a0.y, h1t[1], acc);
      acc = fmaf(a0.z, h1t[2], acc);
      acc = fmaf(a0.w, h1t[3], acc);
      acc = fmaf(a1.x, h1t[4], acc);
      acc = fmaf(a1.y, h1t[5], acc);
      acc = fmaf(a1.z, h1t[6], acc);
      acc = fmaf(a1.w, h1t[7], acc);
      acc = fmaf(a8,   h1t[8], acc);
      if (lane < 32) S->h1[n * 32 + f1] = fmaxf(acc, 0.f);
    }
    WSYNC();  // h1 visible

    // ---- GCN2 matmul: h2t[n] = h1[n,:] . W2[:,lane] ----
    float h2t[9];
#pragma unroll
    for (int n = 0; n < 9; ++n) {
      float acc = 0.f;
#pragma unroll
      for (int q = 0; q < 8; ++q) {
        float4 hv = ((const float4*)S->h1)[n * 8 + q];
        acc = fmaf(hv.x, w2c[q * 4 + 0], acc);
        acc = fmaf(hv.y, w2c[q * 4 + 1], acc);
        acc = fmaf(hv.z, w2c[q * 4 + 2], acc);
        acc = fmaf(hv.w, w2c[q * 4 + 3], acc);
      }
      h2t[n] = acc;
    }

    // ---- GCN2 aggregate + bias + relu; pool ctx; grab station rows ----
    float e0 = 0.f, e8 = 0.f, ctx = 0.f;
#pragma unroll
    for (int n = 0; n < 9; ++n) {
      const float4* Ar = (const float4*)(S->A + n * 12);
      float4 a0 = Ar[0], a1 = Ar[1];
      float  a8 = S->A[n * 12 + 8];
      float acc = b2c;
      acc = fmaf(a0.x, h2t[0], acc);
      acc = fmaf(a0.y, h2t[1], acc);
      acc = fmaf(a0.z, h2t[2], acc);
      acc = fmaf(a0.w, h2t[3], acc);
      acc = fmaf(a1.x, h2t[4], acc);
      acc = fmaf(a1.y, h2t[5], acc);
      acc = fmaf(a1.z, h2t[6], acc);
      acc = fmaf(a1.w, h2t[7], acc);
      acc = fmaf(a8,   h2t[8], acc);
      float r = fmaxf(acc, 0.f);
      ctx += r;
      if (n == 0) e0 = r;
      if (n == 8) e8 = r;
    }
    ctx *= (1.f / 9.f);

    // ---- heads: out[j=lane] = relu(comb . fc1_w[:,j] + b) ; comb via readlane ----
    float acc0 = fc1bc, acc8 = fc1bc, accC = 0.f;
    const float4* Wrow = (const float4*)(fc1T + lane * 132);
#pragma unroll
    for (int q = 0; q < 16; ++q) {          // k = 0..63 : station part (shared W rows)
      float4 wv = Wrow[q];
      acc0 = fmaf(wv.x, rl(e0, 4 * q + 0), acc0);
      acc0 = fmaf(wv.y, rl(e0, 4 * q + 1), acc0);
      acc0 = fmaf(wv.z, rl(e0, 4 * q + 2), acc0);
      acc0 = fmaf(wv.w, rl(e0, 4 * q + 3), acc0);
      acc8 = fmaf(wv.x, rl(e8, 4 * q + 0), acc8);
      acc8 = fmaf(wv.y, rl(e8, 4 * q + 1), acc8);
      acc8 = fmaf(wv.z, rl(e8, 4 * q + 2), acc8);
      acc8 = fmaf(wv.w, rl(e8, 4 * q + 3), acc8);
    }
#pragma unroll
    for (int q = 16; q < 32; ++q) {         // k = 64..127 : ctx part (shared by both heads)
      float4 wv = Wrow[q];
      int kb = 4 * (q - 16);
      accC = fmaf(wv.x, rl(ctx, kb + 0), accC);
      accC = fmaf(wv.y, rl(ctx, kb + 1), accC);
      accC = fmaf(wv.z, rl(ctx, kb + 2), accC);
      accC = fmaf(wv.w, rl(ctx, kb + 3), accC);
    }
    float r0 = fmaxf(acc0 + accC, 0.f);
    float r8 = fmaxf(acc8 + accC, 0.f);

    // ---- fc2 + cross-lane reduce + store ----
    float p0 = r0 * fc2wc;
    float p8 = r8 * fc2wc;
#pragma unroll
    for (int off = 32; off; off >>= 1) {
      p0 += __shfl_xor(p0, off);
      p8 += __shfl_xor(p8, off);
    }
    if (lane == 0) {
      out[2 * g + 0] = p0 + fc2bs;
      out[2 * g + 1] = p8 + fc2bs;
    }
  }
}

extern "C" void kernel_launch(void* const* d_in, const int* in_sizes, int n_in,
                              void* d_out, int out_size, void* d_ws, size_t ws_size,
                              hipStream_t stream) {
  const float* x    = (const float*)d_in[0];
  const int*   ei   = (const int*)d_in[1];
  // d_in[2] = batch (unused: graph id = node/9, counts always 9)
  const float* W1   = (const float*)d_in[3];
  const float* b1   = (const float*)d_in[4];
  const float* W2   = (const float*)d_in[5];
  const float* b2   = (const float*)d_in[6];
  const float* fc1w = (const float*)d_in[7];
  const float* fc1b = (const float*)d_in[8];
  const float* fc2w = (const float*)d_in[9];
  const float* fc2b = (const float*)d_in[10];
  float* out = (float*)d_out;

  hipLaunchKernelGGL(gqn, dim3(GRID), dim3(BLOCK), 0, stream,
                     x, ei, W1, b1, W2, b2, fc1w, fc1b, fc2w, fc2b, out);
}